// Round 1
// baseline (147.868 us; speedup 1.0000x reference)
//
#include <hip/hip_runtime.h>

// ProSurv similarity loss, collapsed:
//   cm[b,c] = (h[b] . bankbar[c]) / max(||h[b]||, eps)
//   bankbar[c] = (1/M) sum_m bank[c,m] / max(||bank[c,m]||, eps)
// then per-sample scalar loss, summed over B and both modalities.

constexpr int NC = 4;     // classes
constexpr int NM = 512;   // prototypes per class
constexpr int ND = 256;   // feature dim
constexpr float EPSF = 1e-12f;

__device__ __forceinline__ float wave_reduce(float v) {
#pragma unroll
    for (int off = 32; off >= 1; off >>= 1)
        v += __shfl_xor(v, off, 64);
    return v;
}

// One wave (64 lanes) per bank row: each lane holds float4 (256 floats/row).
// Normalize row, scale by 1/NM, atomically accumulate into bankbar[bank][c][d].
__global__ __launch_bounds__(64) void bank_prep_kernel(
    const float* __restrict__ pbank, const float* __restrict__ gbank,
    float* __restrict__ bankbar)
{
    const int r      = blockIdx.x;              // 0 .. 2*NC*NM-1
    const int bank   = r >> 11;                 // / (NC*NM) = /2048
    const int within = r & (NC * NM - 1);       // row within bank
    const int c      = within >> 9;             // / NM = /512
    const int lane   = threadIdx.x;

    const float* src = (bank ? gbank : pbank) + (size_t)within * ND;
    const float4 v = reinterpret_cast<const float4*>(src)[lane];
    float ss = v.x * v.x + v.y * v.y + v.z * v.z + v.w * v.w;
    ss = wave_reduce(ss);
    const float inv = 1.0f / (fmaxf(sqrtf(ss), EPSF) * (float)NM);

    float* dst = bankbar + (bank * NC + c) * ND + lane * 4;
    atomicAdd(dst + 0, v.x * inv);
    atomicAdd(dst + 1, v.y * inv);
    atomicAdd(dst + 2, v.z * inv);
    atomicAdd(dst + 3, v.w * inv);
}

// One wave per sample; 4 waves (256 threads) per block; grid = B/4 blocks.
__global__ __launch_bounds__(256) void loss_kernel(
    const float* __restrict__ hp, const float* __restrict__ hg,
    const int* __restrict__ label, const int* __restrict__ censor,
    const float* __restrict__ bankbar, float* __restrict__ out)
{
    __shared__ float sb[2 * NC * ND];   // 8 KiB: both banks' bankbar
    for (int i = threadIdx.x; i < 2 * NC * ND; i += 256)
        sb[i] = bankbar[i];
    __syncthreads();

    const int wave = threadIdx.x >> 6;
    const int lane = threadIdx.x & 63;
    const int b    = blockIdx.x * 4 + wave;   // grid sized exactly B/4

    const int  l   = label[b];
    const bool evt = (censor[b] == 0);

    float cm[2][NC];
#pragma unroll
    for (int md = 0; md < 2; ++md) {
        const float* h  = (md ? hg : hp) + (size_t)b * ND;
        const float4 v  = reinterpret_cast<const float4*>(h)[lane];
        const float* bb = sb + md * NC * ND;

        float s0 = v.x * v.x + v.y * v.y + v.z * v.z + v.w * v.w;
        float sc[NC];
#pragma unroll
        for (int c = 0; c < NC; ++c) {
            const float4 w = reinterpret_cast<const float4*>(bb + c * ND)[lane];
            sc[c] = v.x * w.x + v.y * w.y + v.z * w.z + v.w * w.w;
        }
        // butterfly-reduce 5 values together across the 64-lane wave
#pragma unroll
        for (int off = 32; off >= 1; off >>= 1) {
            s0    += __shfl_xor(s0,    off, 64);
            sc[0] += __shfl_xor(sc[0], off, 64);
            sc[1] += __shfl_xor(sc[1], off, 64);
            sc[2] += __shfl_xor(sc[2], off, 64);
            sc[3] += __shfl_xor(sc[3], off, 64);
        }
        const float invn = 1.0f / fmaxf(sqrtf(s0), EPSF);
#pragma unroll
        for (int c = 0; c < NC; ++c) cm[md][c] = sc[c] * invn;
    }

    // scalar loss (replicated across all lanes; lane 0's value is used)
    float contrib = 0.0f;
#pragma unroll
    for (int md = 0; md < 2; ++md) {
        float sum = 0.f, cml = 0.f, sge = 0.f, slt = 0.f;
#pragma unroll
        for (int c = 0; c < NC; ++c) {
            const float x = cm[md][c];
            sum += x;
            if (c == l) cml = x;
            if (c >= l) sge += x; else slt += x;
        }
        float pos, neg;
        if (evt) {
            pos = cml;
            neg = (sum - cml) * (1.0f / (NC - 1));
        } else {
            // for l==0 this gives pos = sum/NC (pos_all) and neg = 0 — matches ref
            pos = sge / (float)(NC - l);
            neg = slt / (float)(l > 0 ? l : 1);
        }
        contrib += neg - pos;
    }

    __shared__ float wpart[4];
    if (lane == 0) wpart[wave] = contrib;
    __syncthreads();
    if (threadIdx.x == 0)
        atomicAdd(out, wpart[0] + wpart[1] + wpart[2] + wpart[3]);
}

extern "C" void kernel_launch(void* const* d_in, const int* in_sizes, int n_in,
                              void* d_out, int out_size, void* d_ws, size_t ws_size,
                              hipStream_t stream)
{
    const float* hp     = (const float*)d_in[0];
    const float* hg     = (const float*)d_in[1];
    const float* pb     = (const float*)d_in[2];
    const float* gb     = (const float*)d_in[3];
    const int*   label  = (const int*)d_in[4];
    const int*   censor = (const int*)d_in[5];
    float*       out    = (float*)d_out;
    float*       bankbar = (float*)d_ws;   // 2*NC*ND floats = 8 KiB

    const int B = in_sizes[0] / ND;   // 16384

    hipMemsetAsync(bankbar, 0, 2 * NC * ND * sizeof(float), stream);
    hipMemsetAsync(out, 0, sizeof(float), stream);

    bank_prep_kernel<<<2 * NC * NM, 64, 0, stream>>>(pb, gb, bankbar);
    loss_kernel<<<B / 4, 256, 0, stream>>>(hp, hg, label, censor, bankbar, out);
}

// Round 2
// 29.530 us; speedup vs baseline: 5.0073x; 5.0073x over previous
//
#include <hip/hip_runtime.h>

// ProSurv similarity loss, collapsed:
//   cm[b,c] = (h[b] . bankbar[c]) / max(||h[b]||, eps)
//   bankbar[c] = (1/M) sum_m bank[c,m] / max(||bank[c,m]||, eps)
// Fully atomic-free: partial-sum trees through d_ws.

constexpr int NC = 4;     // classes
constexpr int NM = 512;   // prototypes per class
constexpr int ND = 256;   // feature dim
constexpr float EPSF = 1e-12f;

constexpr int SPLIT = 32;                 // segments per (bank,class) combo
constexpr int ROWS_PER_BLOCK = NM / SPLIT;   // 16
constexpr int ROWS_PER_WAVE  = ROWS_PER_BLOCK / 4;  // 4
constexpr int LOSS_BLOCKS = 512;          // 4 waves each, 8 samples per wave

__device__ __forceinline__ float wave_reduce(float v) {
#pragma unroll
    for (int off = 32; off >= 1; off >>= 1)
        v += __shfl_xor(v, off, 64);
    return v;
}

// Stage 1: each block handles 16 rows of one (bank,class) combo.
// Normalizes rows, accumulates sum/NM, writes ONE partial vector per block.
__global__ __launch_bounds__(256) void bank_partial_kernel(
    const float* __restrict__ pbank, const float* __restrict__ gbank,
    float* __restrict__ partials)
{
    const int blk   = blockIdx.x;          // 0 .. 8*SPLIT-1
    const int combo = blk / SPLIT;         // 0..7  (bank*4 + c)
    const int seg   = blk % SPLIT;
    const int bank  = combo >> 2;
    const int c     = combo & 3;
    const int wave  = threadIdx.x >> 6;
    const int lane  = threadIdx.x & 63;

    const float* src = (bank ? gbank : pbank)
        + ((size_t)c * NM + seg * ROWS_PER_BLOCK + wave * ROWS_PER_WAVE) * ND;

    float4 acc = {0.f, 0.f, 0.f, 0.f};
#pragma unroll
    for (int r = 0; r < ROWS_PER_WAVE; ++r) {
        const float4 v = reinterpret_cast<const float4*>(src + (size_t)r * ND)[lane];
        float ss = v.x * v.x + v.y * v.y + v.z * v.z + v.w * v.w;
        ss = wave_reduce(ss);
        const float inv = 1.0f / (fmaxf(sqrtf(ss), EPSF) * (float)NM);
        acc.x += v.x * inv; acc.y += v.y * inv;
        acc.z += v.z * inv; acc.w += v.w * inv;
    }

    // combine the 4 waves' partials through LDS, then one store per block
    __shared__ float4 red[4][64];
    red[wave][lane] = acc;
    __syncthreads();
    if (wave == 0) {
        float4 a = red[0][lane], b = red[1][lane], cc = red[2][lane], d = red[3][lane];
        a.x += b.x + cc.x + d.x; a.y += b.y + cc.y + d.y;
        a.z += b.z + cc.z + d.z; a.w += b.w + cc.w + d.w;
        reinterpret_cast<float4*>(partials + (size_t)blk * ND)[lane] = a;
    }
}

// Stage 2: 8 blocks x 64 lanes; sum the SPLIT partials per combo -> bankbar.
__global__ __launch_bounds__(64) void bank_finalize_kernel(
    const float* __restrict__ partials, float* __restrict__ bankbar)
{
    const int combo = blockIdx.x;
    const int lane  = threadIdx.x;
    float4 acc = {0.f, 0.f, 0.f, 0.f};
#pragma unroll
    for (int s = 0; s < SPLIT; ++s) {
        const float4 v = reinterpret_cast<const float4*>(
            partials + ((size_t)combo * SPLIT + s) * ND)[lane];
        acc.x += v.x; acc.y += v.y; acc.z += v.z; acc.w += v.w;
    }
    reinterpret_cast<float4*>(bankbar + (size_t)combo * ND)[lane] = acc;
}

// Stage 3: one wave per 8 consecutive samples; block partial -> lpart[blk].
__global__ __launch_bounds__(256) void loss_kernel(
    const float* __restrict__ hp, const float* __restrict__ hg,
    const int* __restrict__ label, const int* __restrict__ censor,
    const float* __restrict__ bankbar, float* __restrict__ lpart,
    int samples_per_wave)
{
    __shared__ float sb[2 * NC * ND];   // 8 KiB
    for (int i = threadIdx.x; i < 2 * NC * ND; i += 256)
        sb[i] = bankbar[i];
    __syncthreads();

    const int wave = threadIdx.x >> 6;
    const int lane = threadIdx.x & 63;
    const int wid  = blockIdx.x * 4 + wave;

    float contrib = 0.0f;
    for (int i = 0; i < samples_per_wave; ++i) {
        const int b = wid * samples_per_wave + i;
        const int  l   = label[b];
        const bool evt = (censor[b] == 0);

        float cm[2][NC];
#pragma unroll
        for (int md = 0; md < 2; ++md) {
            const float* h  = (md ? hg : hp) + (size_t)b * ND;
            const float4 v  = reinterpret_cast<const float4*>(h)[lane];
            const float* bb = sb + md * NC * ND;

            float s0 = v.x * v.x + v.y * v.y + v.z * v.z + v.w * v.w;
            float sc[NC];
#pragma unroll
            for (int c = 0; c < NC; ++c) {
                const float4 w = reinterpret_cast<const float4*>(bb + c * ND)[lane];
                sc[c] = v.x * w.x + v.y * w.y + v.z * w.z + v.w * w.w;
            }
#pragma unroll
            for (int off = 32; off >= 1; off >>= 1) {
                s0    += __shfl_xor(s0,    off, 64);
                sc[0] += __shfl_xor(sc[0], off, 64);
                sc[1] += __shfl_xor(sc[1], off, 64);
                sc[2] += __shfl_xor(sc[2], off, 64);
                sc[3] += __shfl_xor(sc[3], off, 64);
            }
            const float invn = 1.0f / fmaxf(sqrtf(s0), EPSF);
#pragma unroll
            for (int c = 0; c < NC; ++c) cm[md][c] = sc[c] * invn;
        }

#pragma unroll
        for (int md = 0; md < 2; ++md) {
            float sum = 0.f, cml = 0.f, sge = 0.f, slt = 0.f;
#pragma unroll
            for (int c = 0; c < NC; ++c) {
                const float x = cm[md][c];
                sum += x;
                if (c == l) cml = x;
                if (c >= l) sge += x; else slt += x;
            }
            float pos, neg;
            if (evt) {
                pos = cml;
                neg = (sum - cml) * (1.0f / (NC - 1));
            } else {
                pos = sge / (float)(NC - l);          // l==0 -> sum/NC (pos_all)
                neg = slt / (float)(l > 0 ? l : 1);   // l==0 -> 0
            }
            contrib += neg - pos;
        }
    }

    __shared__ float wpart[4];
    if (lane == 0) wpart[wave] = contrib;
    __syncthreads();
    if (threadIdx.x == 0)
        lpart[blockIdx.x] = wpart[0] + wpart[1] + wpart[2] + wpart[3];
}

// Stage 4: one block sums the LOSS_BLOCKS partials -> out[0].
__global__ __launch_bounds__(256) void final_kernel(
    const float* __restrict__ lpart, float* __restrict__ out)
{
    const int t = threadIdx.x;
    float v = lpart[t] + lpart[t + 256];
    v = wave_reduce(v);
    __shared__ float wp[4];
    if ((t & 63) == 0) wp[t >> 6] = v;
    __syncthreads();
    if (t == 0) out[0] = wp[0] + wp[1] + wp[2] + wp[3];
}

extern "C" void kernel_launch(void* const* d_in, const int* in_sizes, int n_in,
                              void* d_out, int out_size, void* d_ws, size_t ws_size,
                              hipStream_t stream)
{
    const float* hp     = (const float*)d_in[0];
    const float* hg     = (const float*)d_in[1];
    const float* pb     = (const float*)d_in[2];
    const float* gb     = (const float*)d_in[3];
    const int*   label  = (const int*)d_in[4];
    const int*   censor = (const int*)d_in[5];
    float*       out    = (float*)d_out;

    float* partials = (float*)d_ws;                         // 8*SPLIT*ND = 256 KiB
    float* bankbar  = partials + (size_t)8 * SPLIT * ND;    // 8 KiB
    float* lpart    = bankbar + 2 * NC * ND;                // LOSS_BLOCKS floats

    const int B = in_sizes[0] / ND;                         // 16384
    const int samples_per_wave = B / (LOSS_BLOCKS * 4);     // 8

    bank_partial_kernel <<<8 * SPLIT, 256, 0, stream>>>(pb, gb, partials);
    bank_finalize_kernel<<<8,         64,  0, stream>>>(partials, bankbar);
    loss_kernel         <<<LOSS_BLOCKS, 256, 0, stream>>>(hp, hg, label, censor,
                                                          bankbar, lpart, samples_per_wave);
    final_kernel        <<<1, 256, 0, stream>>>(lpart, out);
}